// Round 3
// baseline (348.015 us; speedup 1.0000x reference)
//
#include <hip/hip_runtime.h>
#include <stdint.h>

#define S_LEN 4096
#define DM 1024
#define NH 16

typedef __attribute__((ext_vector_type(8))) short short8;
typedef __attribute__((ext_vector_type(4))) float float4v;
typedef __attribute__((ext_vector_type(4))) unsigned short ushort4v;

typedef __attribute__((address_space(1))) const void* as1cvp;
typedef __attribute__((address_space(3))) void* as3vp;

#define MFMA16(a, b, c) __builtin_amdgcn_mfma_f32_16x16x32_bf16((a), (b), (c), 0, 0, 0)
#define GLOAD_LDS16(g, l) \
  __builtin_amdgcn_global_load_lds((as1cvp)(g), (as3vp)(l), 16, 0, 0)

__device__ __forceinline__ unsigned short f2bf(float f) {
  unsigned u = __float_as_uint(f);
  u += 0x7fffu + ((u >> 16) & 1u);
  return (unsigned short)(u >> 16);
}

// ---------------- cast fp32 -> bf16 into workspace ----------------
__global__ __launch_bounds__(256) void cast_all(
    const float* __restrict__ q, const float* __restrict__ k, const float* __restrict__ v,
    const float* __restrict__ wq, const float* __restrict__ wk, const float* __restrict__ wv,
    const float* __restrict__ wo, unsigned short* __restrict__ dst)
{
  const float* src; size_t off; int n;
  switch (blockIdx.y) {
    case 0: src = q;  off = 0u;        n = 4194304; break;
    case 1: src = k;  off = 4194304u;  n = 4194304; break;
    case 2: src = v;  off = 8388608u;  n = 4194304; break;
    case 3: src = wq; off = 12582912u; n = 1048576; break;
    case 4: src = wk; off = 13631488u; n = 1048576; break;
    case 5: src = wv; off = 14680064u; n = 1048576; break;
    default: src = wo; off = 15728640u; n = 1048576; break;
  }
  int nv = n >> 2;
  for (int i = blockIdx.x * blockDim.x + threadIdx.x; i < nv; i += gridDim.x * blockDim.x) {
    float4v val = ((const float4v*)src)[i];
    ushort4v o;
    o.x = f2bf(val.x); o.y = f2bf(val.y); o.z = f2bf(val.z); o.w = f2bf(val.w);
    ((ushort4v*)(dst + off))[i] = o;
  }
}

// ---------------- 128x128 bt-GEMM tile (m97 structure) ----------------
// A: [4096][1024] bf16 row-major; Bw: [1024][1024] bf16 row-major (= B^T, k contiguous)
// MODE 0: bf16 row-major out; MODE 1: f32 row-major out; MODE 2: bf16 TRANSPOSED out [N][4096]
template<int MODE>
__device__ __forceinline__ void gemm128(
    const unsigned short* __restrict__ A, const unsigned short* __restrict__ Bw,
    unsigned short* Cb, float* Cf, const float* __restrict__ bias, float alpha,
    unsigned short* As, unsigned short* Bs)
{
  const int K = 1024, N = 1024;
  int bm = blockIdx.x, bn = blockIdx.y;
  int t = threadIdx.x, lane = t & 63, w = t >> 6;
  int l15 = lane & 15, l4 = lane >> 4;
  int wr = w >> 1, wc = w & 1;

  float4v acc[4][4] = {};

  for (int kt = 0; kt < K / 32; ++kt) {
#pragma unroll
    for (int i = 0; i < 2; ++i) {
      int ci = i * 256 + t;
      int r = ci >> 2, cb = ci & 3;
      GLOAD_LDS16(A + (size_t)(bm * 128 + r) * K + kt * 32 + cb * 8,
                  As + (size_t)(i * 256 + w * 64) * 8);
      GLOAD_LDS16(Bw + (size_t)(bn * 128 + r) * K + kt * 32 + cb * 8,
                  Bs + (size_t)(i * 256 + w * 64) * 8);
    }
    __syncthreads();
    short8 af[4], bfr[4];
#pragma unroll
    for (int mf = 0; mf < 4; ++mf)
      af[mf] = *(const short8*)&As[(wr * 64 + mf * 16 + l15) * 32 + l4 * 8];
#pragma unroll
    for (int nf = 0; nf < 4; ++nf)
      bfr[nf] = *(const short8*)&Bs[(wc * 64 + nf * 16 + l15) * 32 + l4 * 8];
#pragma unroll
    for (int mf = 0; mf < 4; ++mf)
#pragma unroll
      for (int nf = 0; nf < 4; ++nf)
        acc[mf][nf] = MFMA16(af[mf], bfr[nf], acc[mf][nf]);
    __syncthreads();
  }

#pragma unroll
  for (int mf = 0; mf < 4; ++mf)
#pragma unroll
    for (int nf = 0; nf < 4; ++nf) {
      int col = bn * 128 + wc * 64 + nf * 16 + l15;
      float bv = bias[col];
#pragma unroll
      for (int j = 0; j < 4; ++j) {
        int row = bm * 128 + wr * 64 + mf * 16 + l4 * 4 + j;
        float val = (acc[mf][nf][j] + bv) * alpha;
        if (MODE == 1)      Cf[(size_t)row * N + col] = val;
        else if (MODE == 2) Cb[(size_t)col * S_LEN + row] = f2bf(val);  // transposed
        else                Cb[(size_t)row * N + col] = f2bf(val);
      }
    }
}

__global__ __launch_bounds__(256) void proj_qkv(
    const unsigned short* xq, const unsigned short* xk, const unsigned short* xv,
    const unsigned short* wq, const unsigned short* wk, const unsigned short* wv,
    unsigned short* Qp, unsigned short* Kp, unsigned short* Vt,
    const float* bq, const float* bk, const float* bv)
{
  __shared__ unsigned short As[128 * 32], Bs[128 * 32];
  switch (blockIdx.z) {
    case 0:  gemm128<0>(xq, wq, Qp, nullptr, bq, 0.125f, As, Bs); break; // 1/sqrt(64) folded
    case 1:  gemm128<0>(xk, wk, Kp, nullptr, bk, 1.0f,   As, Bs); break;
    default: gemm128<2>(xv, wv, Vt, nullptr, bv, 1.0f,   As, Bs); break; // V^T [1024][4096]
  }
}

__global__ __launch_bounds__(256) void proj_o(
    const unsigned short* ctx, const unsigned short* wo, float* out, const float* bo)
{
  __shared__ unsigned short As[128 * 32], Bs[128 * 32];
  gemm128<1>(ctx, wo, nullptr, out, bo, 1.0f, As, Bs);
}

// ---------------- fused flash attention ----------------
// block = (head h, 128 q rows). 4 waves x 32 rows. KV tile = 64.
// K staged linearly [64][64]; V^T staged linearly [64 d][64 k]. No swizzle this round.
__global__ __launch_bounds__(256) void attn_fused(
    const unsigned short* __restrict__ Qp, const unsigned short* __restrict__ Kp,
    const unsigned short* __restrict__ Vt, unsigned short* __restrict__ ctx)
{
  __shared__ unsigned short Ks[64 * 64];
  __shared__ unsigned short Vts[64 * 64];
  __shared__ unsigned short Ps[4][32 * 88];  // per-wave P, row stride 88 (16B aligned)

  int h = blockIdx.y, qt = blockIdx.x;
  int t = threadIdx.x, lane = t & 63, w = t >> 6;
  int l15 = lane & 15, l4 = lane >> 4;

  // Q fragments in registers (already scaled by 1/8 in projection)
  short8 qf[2][2];
  int qrow0 = qt * 128 + w * 32;
#pragma unroll
  for (int mf = 0; mf < 2; ++mf)
#pragma unroll
    for (int ks = 0; ks < 2; ++ks)
      qf[mf][ks] = *(const short8*)&Qp[(size_t)(qrow0 + mf * 16 + l15) * DM + h * 64 + ks * 32 + l4 * 8];

  float4v acc_o[2][4] = {};
  float m_run[2][4], l_run[2][4];
#pragma unroll
  for (int mf = 0; mf < 2; ++mf)
#pragma unroll
    for (int j = 0; j < 4; ++j) { m_run[mf][j] = -INFINITY; l_run[mf][j] = 0.f; }

  unsigned short* Pw = Ps[w];

  for (int kt = 0; kt < 64; ++kt) {
    // ---- stage K tile [64][64] and V^T tile [64 d][64 k], both linear ----
#pragma unroll
    for (int i = 0; i < 2; ++i) {
      int ci = i * 256 + t;
      int r = ci >> 3, blk = ci & 7;
      GLOAD_LDS16(Kp + (size_t)(kt * 64 + r) * DM + h * 64 + blk * 8,
                  Ks + (size_t)(i * 256 + w * 64) * 8);
      GLOAD_LDS16(Vt + (size_t)(h * 64 + r) * S_LEN + kt * 64 + blk * 8,
                  Vts + (size_t)(i * 256 + w * 64) * 8);
    }
    __syncthreads();

    // ---- QK^T ----
    float4v sc[2][4] = {};
#pragma unroll
    for (int nf = 0; nf < 4; ++nf) {
#pragma unroll
      for (int ks = 0; ks < 2; ++ks) {
        short8 kf = *(const short8*)&Ks[(nf * 16 + l15) * 64 + ks * 32 + l4 * 8];
        sc[0][nf] = MFMA16(qf[0][ks], kf, sc[0][nf]);
        sc[1][nf] = MFMA16(qf[1][ks], kf, sc[1][nf]);
      }
    }

    // ---- online softmax (rows: l4*4+j per mf), write P to per-wave LDS ----
#pragma unroll
    for (int mf = 0; mf < 2; ++mf)
#pragma unroll
      for (int j = 0; j < 4; ++j) {
        float mx = fmaxf(fmaxf(sc[mf][0][j], sc[mf][1][j]), fmaxf(sc[mf][2][j], sc[mf][3][j]));
#pragma unroll
        for (int msk = 1; msk < 16; msk <<= 1) mx = fmaxf(mx, __shfl_xor(mx, msk));
        float mnew = fmaxf(m_run[mf][j], mx);
        float corr = __expf(m_run[mf][j] - mnew);
        float ps = 0.f;
#pragma unroll
        for (int nf = 0; nf < 4; ++nf) {
          float p = __expf(sc[mf][nf][j] - mnew);
          ps += p;
          Pw[(mf * 16 + l4 * 4 + j) * 88 + nf * 16 + l15] = f2bf(p);
        }
#pragma unroll
        for (int msk = 1; msk < 16; msk <<= 1) ps += __shfl_xor(ps, msk);
        m_run[mf][j] = mnew;
        l_run[mf][j] = l_run[mf][j] * corr + ps;
        // rescale ONLY this row's accumulator component (j)
#pragma unroll
        for (int nf2 = 0; nf2 < 4; ++nf2) acc_o[mf][nf2][j] *= corr;
      }

    // ---- P A-fragments from LDS ----
    short8 pf[2][2];
#pragma unroll
    for (int mf = 0; mf < 2; ++mf)
#pragma unroll
      for (int kc = 0; kc < 2; ++kc)
        pf[mf][kc] = *(const short8*)&Pw[(mf * 16 + l15) * 88 + kc * 32 + l4 * 8];

    // ---- V^T B-fragments: lane holds V[k = kc*32+l4*8+e][d = nfd*16+l15] ----
#pragma unroll
    for (int nfd = 0; nfd < 4; ++nfd)
#pragma unroll
      for (int kc = 0; kc < 2; ++kc) {
        short8 vf = *(const short8*)&Vts[(nfd * 16 + l15) * 64 + kc * 32 + l4 * 8];
        acc_o[0][nfd] = MFMA16(pf[0][kc], vf, acc_o[0][nfd]);
        acc_o[1][nfd] = MFMA16(pf[1][kc], vf, acc_o[1][nfd]);
      }
    __syncthreads();
  }

  // ---- normalize + write ctx (bf16) ----
#pragma unroll
  for (int mf = 0; mf < 2; ++mf)
#pragma unroll
    for (int nfd = 0; nfd < 4; ++nfd)
#pragma unroll
      for (int j = 0; j < 4; ++j) {
        int row = qt * 128 + w * 32 + mf * 16 + l4 * 4 + j;
        int col = h * 64 + nfd * 16 + l15;
        ctx[(size_t)row * DM + col] = f2bf(acc_o[mf][nfd][j] / l_run[mf][j]);
      }
}

// ---------------- launcher ----------------
extern "C" void kernel_launch(void* const* d_in, const int* in_sizes, int n_in,
                              void* d_out, int out_size, void* d_ws, size_t ws_size,
                              hipStream_t stream) {
  const float* q  = (const float*)d_in[0];
  const float* k  = (const float*)d_in[1];
  const float* v  = (const float*)d_in[2];
  const float* wq = (const float*)d_in[3];
  const float* bq = (const float*)d_in[4];
  const float* wk = (const float*)d_in[5];
  const float* bk = (const float*)d_in[6];
  const float* wv = (const float*)d_in[7];
  const float* bv = (const float*)d_in[8];
  const float* wo = (const float*)d_in[9];
  const float* bo = (const float*)d_in[10];

  unsigned short* ws  = (unsigned short*)d_ws;
  unsigned short* qb  = ws;                 // 4M elems (reused as ctx later)
  unsigned short* kb  = ws + 4194304u;
  unsigned short* vb  = ws + 8388608u;
  unsigned short* wqb = ws + 12582912u;
  unsigned short* wkb = ws + 13631488u;
  unsigned short* wvb = ws + 14680064u;
  unsigned short* wob = ws + 15728640u;
  unsigned short* Qp  = ws + 16777216u;
  unsigned short* Kp  = ws + 20971520u;
  unsigned short* Vt  = ws + 25165824u;     // V^T [1024][4096]
  unsigned short* ctx = qb;                 // safe reuse: qb consumed by proj_qkv before attn
  float* out = (float*)d_out;

  cast_all<<<dim3(1024, 7), 256, 0, stream>>>(q, k, v, wq, wk, wv, wo, ws);
  proj_qkv<<<dim3(32, 8, 3), 256, 0, stream>>>(qb, kb, vb, wqb, wkb, wvb, Qp, Kp, Vt, bq, bk, bv);
  attn_fused<<<dim3(32, 16), 256, 0, stream>>>(Qp, Kp, Vt, ctx);
  proj_o<<<dim3(32, 8), 256, 0, stream>>>(ctx, wob, out, bo);
}

// Round 4
// 315.102 us; speedup vs baseline: 1.1045x; 1.1045x over previous
//
#include <hip/hip_runtime.h>
#include <stdint.h>

#define S_LEN 4096
#define DM 1024
#define NH 16

typedef __attribute__((ext_vector_type(8))) short short8;
typedef __attribute__((ext_vector_type(4))) float float4v;
typedef __attribute__((ext_vector_type(4))) unsigned short ushort4v;

typedef __attribute__((address_space(1))) const void* as1cvp;
typedef __attribute__((address_space(3))) void* as3vp;

#define MFMA16(a, b, c) __builtin_amdgcn_mfma_f32_16x16x32_bf16((a), (b), (c), 0, 0, 0)
#define GLOAD_LDS16(g, l) \
  __builtin_amdgcn_global_load_lds((as1cvp)(g), (as3vp)(l), 16, 0, 0)

__device__ __forceinline__ unsigned short f2bf(float f) {
  unsigned u = __float_as_uint(f);
  u += 0x7fffu + ((u >> 16) & 1u);
  return (unsigned short)(u >> 16);
}

// ---------------- cast fp32 -> bf16 into workspace ----------------
__global__ __launch_bounds__(256) void cast_all(
    const float* __restrict__ q, const float* __restrict__ k, const float* __restrict__ v,
    const float* __restrict__ wq, const float* __restrict__ wk, const float* __restrict__ wv,
    const float* __restrict__ wo, unsigned short* __restrict__ dst)
{
  const float* src; size_t off; int n;
  switch (blockIdx.y) {
    case 0: src = q;  off = 0u;        n = 4194304; break;
    case 1: src = k;  off = 4194304u;  n = 4194304; break;
    case 2: src = v;  off = 8388608u;  n = 4194304; break;
    case 3: src = wq; off = 12582912u; n = 1048576; break;
    case 4: src = wk; off = 13631488u; n = 1048576; break;
    case 5: src = wv; off = 14680064u; n = 1048576; break;
    default: src = wo; off = 15728640u; n = 1048576; break;
  }
  int nv = n >> 2;
  for (int i = blockIdx.x * blockDim.x + threadIdx.x; i < nv; i += gridDim.x * blockDim.x) {
    float4v val = ((const float4v*)src)[i];
    ushort4v o;
    o.x = f2bf(val.x); o.y = f2bf(val.y); o.z = f2bf(val.z); o.w = f2bf(val.w);
    ((ushort4v*)(dst + off))[i] = o;
  }
}

// ---------------- 128x128 bt-GEMM tile (m97 structure) ----------------
// A: [4096][1024] bf16 row-major; Bw: [1024][1024] bf16 row-major (= B^T, k contiguous)
// MODE 0: bf16 row-major out; MODE 1: f32 row-major out; MODE 2: bf16 TRANSPOSED out [N][4096]
template<int MODE>
__device__ __forceinline__ void gemm128(
    const unsigned short* __restrict__ A, const unsigned short* __restrict__ Bw,
    unsigned short* Cb, float* Cf, const float* __restrict__ bias, float alpha,
    unsigned short* As, unsigned short* Bs)
{
  const int K = 1024, N = 1024;
  int bm = blockIdx.x, bn = blockIdx.y;
  int t = threadIdx.x, lane = t & 63, w = t >> 6;
  int l15 = lane & 15, l4 = lane >> 4;
  int wr = w >> 1, wc = w & 1;

  float4v acc[4][4] = {};

  for (int kt = 0; kt < K / 32; ++kt) {
#pragma unroll
    for (int i = 0; i < 2; ++i) {
      int ci = i * 256 + t;
      int r = ci >> 2, cb = ci & 3;
      GLOAD_LDS16(A + (size_t)(bm * 128 + r) * K + kt * 32 + cb * 8,
                  As + (size_t)(i * 256 + w * 64) * 8);
      GLOAD_LDS16(Bw + (size_t)(bn * 128 + r) * K + kt * 32 + cb * 8,
                  Bs + (size_t)(i * 256 + w * 64) * 8);
    }
    __syncthreads();
    short8 af[4], bfr[4];
#pragma unroll
    for (int mf = 0; mf < 4; ++mf)
      af[mf] = *(const short8*)&As[(wr * 64 + mf * 16 + l15) * 32 + l4 * 8];
#pragma unroll
    for (int nf = 0; nf < 4; ++nf)
      bfr[nf] = *(const short8*)&Bs[(wc * 64 + nf * 16 + l15) * 32 + l4 * 8];
#pragma unroll
    for (int mf = 0; mf < 4; ++mf)
#pragma unroll
      for (int nf = 0; nf < 4; ++nf)
        acc[mf][nf] = MFMA16(af[mf], bfr[nf], acc[mf][nf]);
    __syncthreads();
  }

#pragma unroll
  for (int mf = 0; mf < 4; ++mf)
#pragma unroll
    for (int nf = 0; nf < 4; ++nf) {
      int col = bn * 128 + wc * 64 + nf * 16 + l15;
      float bv = bias[col];
#pragma unroll
      for (int j = 0; j < 4; ++j) {
        int row = bm * 128 + wr * 64 + mf * 16 + l4 * 4 + j;
        float val = (acc[mf][nf][j] + bv) * alpha;
        if (MODE == 1)      Cf[(size_t)row * N + col] = val;
        else if (MODE == 2) Cb[(size_t)col * S_LEN + row] = f2bf(val);  // transposed
        else                Cb[(size_t)row * N + col] = f2bf(val);
      }
    }
}

__global__ __launch_bounds__(256) void proj_qkv(
    const unsigned short* xq, const unsigned short* xk, const unsigned short* xv,
    const unsigned short* wq, const unsigned short* wk, const unsigned short* wv,
    unsigned short* Qp, unsigned short* Kp, unsigned short* Vt,
    const float* bq, const float* bk, const float* bv)
{
  __shared__ unsigned short As[128 * 32], Bs[128 * 32];
  switch (blockIdx.z) {
    case 0:  gemm128<0>(xq, wq, Qp, nullptr, bq, 0.125f, As, Bs); break; // 1/sqrt(64) folded
    case 1:  gemm128<0>(xk, wk, Kp, nullptr, bk, 1.0f,   As, Bs); break;
    default: gemm128<2>(xv, wv, Vt, nullptr, bv, 1.0f,   As, Bs); break; // V^T [1024][4096]
  }
}

__global__ __launch_bounds__(256) void proj_o(
    const unsigned short* ctx, const unsigned short* wo, float* out, const float* bo)
{
  __shared__ unsigned short As[128 * 32], Bs[128 * 32];
  gemm128<1>(ctx, wo, nullptr, out, bo, 1.0f, As, Bs);
}

// ---------------- fused flash attention ----------------
// 1024 blocks (XCD-swizzled), block = (head h, 64 q rows), 4 waves x 16 rows.
// KV tile = 64, double-buffered; K and V^T tiles XOR-swizzled (16B block ^= row&7)
// via pre-swizzled global source + same XOR on read (rule #21 both-sides).
__global__ __launch_bounds__(256) void attn_fused(
    const unsigned short* __restrict__ Qp, const unsigned short* __restrict__ Kp,
    const unsigned short* __restrict__ Vt, unsigned short* __restrict__ ctx)
{
  __shared__ unsigned short Ks[2][64 * 64];
  __shared__ unsigned short Vts[2][64 * 64];
  __shared__ unsigned short Ps[4][16 * 88];  // per-wave P, row stride 88 (odd*16B: conflict-free b128)

  // bijective XCD swizzle: 1024 blocks, 8 XCDs, 128 consecutive wg per XCD (= 2 heads)
  int bid = blockIdx.x;
  int wg = (bid & 7) * 128 + (bid >> 3);
  int h = wg >> 6, qt = wg & 63;

  int t = threadIdx.x, lane = t & 63, w = t >> 6;
  int l15 = lane & 15, l4 = lane >> 4;

  // Q fragments in registers (already scaled by 1/8 in projection)
  short8 qf[2];
  int qrow0 = qt * 64 + w * 16;
#pragma unroll
  for (int ks = 0; ks < 2; ++ks)
    qf[ks] = *(const short8*)&Qp[(size_t)(qrow0 + l15) * DM + h * 64 + ks * 32 + l4 * 8];

  float4v acc_o[4] = {};
  float m_run[4], l_run[4];
#pragma unroll
  for (int j = 0; j < 4; ++j) { m_run[j] = -INFINITY; l_run[j] = 0.f; }

  unsigned short* Pw = Ps[w];

#define STAGE_KV(buf, kt) do {                                              \
    _Pragma("unroll")                                                       \
    for (int i = 0; i < 2; ++i) {                                           \
      int ci = i * 256 + t;                                                 \
      int r = ci >> 3, p = ci & 7;                                          \
      int lb = p ^ (r & 7);                                                 \
      GLOAD_LDS16(Kp + (size_t)((kt) * 64 + r) * DM + h * 64 + lb * 8,      \
                  &Ks[buf][(size_t)(i * 256 + w * 64) * 8]);                \
      GLOAD_LDS16(Vt + (size_t)(h * 64 + r) * S_LEN + (kt) * 64 + lb * 8,   \
                  &Vts[buf][(size_t)(i * 256 + w * 64) * 8]);               \
    }                                                                       \
  } while (0)

  STAGE_KV(0, 0);
  __syncthreads();
  int cur = 0;

  for (int kt = 0; kt < 64; ++kt) {
    if (kt + 1 < 64) STAGE_KV(cur ^ 1, kt + 1);   // prefetch next tile (in flight under compute)

    // ---- QK^T ----
    float4v sc[4] = {};
#pragma unroll
    for (int nf = 0; nf < 4; ++nf)
#pragma unroll
      for (int ks = 0; ks < 2; ++ks) {
        int row = nf * 16 + l15;
        int pb = (ks * 4 + l4) ^ (row & 7);
        short8 kf = *(const short8*)&Ks[cur][row * 64 + pb * 8];
        sc[nf] = MFMA16(qf[ks], kf, sc[nf]);
      }

    // ---- online softmax (row = l4*4+j), write P to per-wave LDS ----
#pragma unroll
    for (int j = 0; j < 4; ++j) {
      float mx = fmaxf(fmaxf(sc[0][j], sc[1][j]), fmaxf(sc[2][j], sc[3][j]));
#pragma unroll
      for (int msk = 1; msk < 16; msk <<= 1) mx = fmaxf(mx, __shfl_xor(mx, msk));
      float mnew = fmaxf(m_run[j], mx);
      float corr = __expf(m_run[j] - mnew);
      float ps = 0.f;
#pragma unroll
      for (int nf = 0; nf < 4; ++nf) {
        float p = __expf(sc[nf][j] - mnew);
        ps += p;
        Pw[(l4 * 4 + j) * 88 + nf * 16 + l15] = f2bf(p);
      }
#pragma unroll
      for (int msk = 1; msk < 16; msk <<= 1) ps += __shfl_xor(ps, msk);
      m_run[j] = mnew;
      l_run[j] = l_run[j] * corr + ps;
#pragma unroll
      for (int nf2 = 0; nf2 < 4; ++nf2) acc_o[nf2][j] *= corr;
    }

    // ---- P A-fragments from LDS ----
    short8 pf[2];
#pragma unroll
    for (int kc = 0; kc < 2; ++kc)
      pf[kc] = *(const short8*)&Pw[l15 * 88 + kc * 32 + l4 * 8];

    // ---- PV: V^T B-fragments (swizzled read) ----
#pragma unroll
    for (int nfd = 0; nfd < 4; ++nfd)
#pragma unroll
      for (int kc = 0; kc < 2; ++kc) {
        int row = nfd * 16 + l15;
        int pb = (kc * 4 + l4) ^ (row & 7);
        short8 vf = *(const short8*)&Vts[cur][row * 64 + pb * 8];
        acc_o[nfd] = MFMA16(pf[kc], vf, acc_o[nfd]);
      }

    __syncthreads();   // drains prefetch (vmcnt auto) + all waves done with buf[cur]
    cur ^= 1;
  }
#undef STAGE_KV

  // ---- normalize + write ctx (bf16) ----
#pragma unroll
  for (int nfd = 0; nfd < 4; ++nfd)
#pragma unroll
    for (int j = 0; j < 4; ++j) {
      int row = qt * 64 + w * 16 + l4 * 4 + j;
      int col = h * 64 + nfd * 16 + l15;
      ctx[(size_t)row * DM + col] = f2bf(acc_o[nfd][j] / l_run[j]);
    }
}

// ---------------- launcher ----------------
extern "C" void kernel_launch(void* const* d_in, const int* in_sizes, int n_in,
                              void* d_out, int out_size, void* d_ws, size_t ws_size,
                              hipStream_t stream) {
  const float* q  = (const float*)d_in[0];
  const float* k  = (const float*)d_in[1];
  const float* v  = (const float*)d_in[2];
  const float* wq = (const float*)d_in[3];
  const float* bq = (const float*)d_in[4];
  const float* wk = (const float*)d_in[5];
  const float* bk = (const float*)d_in[6];
  const float* wv = (const float*)d_in[7];
  const float* bv = (const float*)d_in[8];
  const float* wo = (const float*)d_in[9];
  const float* bo = (const float*)d_in[10];

  unsigned short* ws  = (unsigned short*)d_ws;
  unsigned short* qb  = ws;                 // 4M elems (reused as ctx later)
  unsigned short* kb  = ws + 4194304u;
  unsigned short* vb  = ws + 8388608u;
  unsigned short* wqb = ws + 12582912u;
  unsigned short* wkb = ws + 13631488u;
  unsigned short* wvb = ws + 14680064u;
  unsigned short* wob = ws + 15728640u;
  unsigned short* Qp  = ws + 16777216u;
  unsigned short* Kp  = ws + 20971520u;
  unsigned short* Vt  = ws + 25165824u;     // V^T [1024][4096]
  unsigned short* ctx = qb;                 // safe reuse: qb consumed by proj_qkv before attn
  float* out = (float*)d_out;

  cast_all<<<dim3(1024, 7), 256, 0, stream>>>(q, k, v, wq, wk, wv, wo, ws);
  proj_qkv<<<dim3(32, 8, 3), 256, 0, stream>>>(qb, kb, vb, wqb, wkb, wvb, Qp, Kp, Vt, bq, bk, bv);
  attn_fused<<<dim3(1024), 256, 0, stream>>>(Qp, Kp, Vt, ctx);
  proj_o<<<dim3(32, 8), 256, 0, stream>>>(ctx, wob, out, bo);
}

// Round 5
// 242.817 us; speedup vs baseline: 1.4332x; 1.2977x over previous
//
#include <hip/hip_runtime.h>
#include <stdint.h>

#define S_LEN 4096
#define DM 1024
#define NH 16

typedef __attribute__((ext_vector_type(8))) short short8;
typedef __attribute__((ext_vector_type(4))) float float4v;
typedef __attribute__((ext_vector_type(4))) unsigned short ushort4v;

typedef __attribute__((address_space(1))) const void* as1cvp;
typedef __attribute__((address_space(3))) void* as3vp;

#define MFMA16(a, b, c) __builtin_amdgcn_mfma_f32_16x16x32_bf16((a), (b), (c), 0, 0, 0)
#define GLOAD_LDS16(g, l) \
  __builtin_amdgcn_global_load_lds((as1cvp)(g), (as3vp)(l), 16, 0, 0)

__device__ __forceinline__ unsigned short f2bf(float f) {
  unsigned u = __float_as_uint(f);
  u += 0x7fffu + ((u >> 16) & 1u);
  return (unsigned short)(u >> 16);
}

// ---------------- cast fp32 -> bf16 into workspace ----------------
__global__ __launch_bounds__(256) void cast_all(
    const float* __restrict__ q, const float* __restrict__ k, const float* __restrict__ v,
    const float* __restrict__ wq, const float* __restrict__ wk, const float* __restrict__ wv,
    const float* __restrict__ wo, unsigned short* __restrict__ dst)
{
  const float* src; size_t off; int n;
  switch (blockIdx.y) {
    case 0: src = q;  off = 0u;        n = 4194304; break;
    case 1: src = k;  off = 4194304u;  n = 4194304; break;
    case 2: src = v;  off = 8388608u;  n = 4194304; break;
    case 3: src = wq; off = 12582912u; n = 1048576; break;
    case 4: src = wk; off = 13631488u; n = 1048576; break;
    case 5: src = wv; off = 14680064u; n = 1048576; break;
    default: src = wo; off = 15728640u; n = 1048576; break;
  }
  int nv = n >> 2;
  for (int i = blockIdx.x * blockDim.x + threadIdx.x; i < nv; i += gridDim.x * blockDim.x) {
    float4v val = ((const float4v*)src)[i];
    ushort4v o;
    o.x = f2bf(val.x); o.y = f2bf(val.y); o.z = f2bf(val.z); o.w = f2bf(val.w);
    ((ushort4v*)(dst + off))[i] = o;
  }
}

// ---------------- 128x128 bt-GEMM tile (m97 structure) ----------------
// A: [4096][1024] bf16 row-major; Bw: [1024][1024] bf16 row-major (= B^T, k contiguous)
// MODE 0: bf16 row-major out; MODE 1: f32 row-major out; MODE 2: bf16 TRANSPOSED out [N][4096]
template<int MODE>
__device__ __forceinline__ void gemm128(
    const unsigned short* __restrict__ A, const unsigned short* __restrict__ Bw,
    unsigned short* Cb, float* Cf, const float* __restrict__ bias, float alpha,
    unsigned short* As, unsigned short* Bs)
{
  const int K = 1024, N = 1024;
  int bm = blockIdx.x, bn = blockIdx.y;
  int t = threadIdx.x, lane = t & 63, w = t >> 6;
  int l15 = lane & 15, l4 = lane >> 4;
  int wr = w >> 1, wc = w & 1;

  float4v acc[4][4] = {};

  for (int kt = 0; kt < K / 32; ++kt) {
#pragma unroll
    for (int i = 0; i < 2; ++i) {
      int ci = i * 256 + t;
      int r = ci >> 2, cb = ci & 3;
      GLOAD_LDS16(A + (size_t)(bm * 128 + r) * K + kt * 32 + cb * 8,
                  As + (size_t)(i * 256 + w * 64) * 8);
      GLOAD_LDS16(Bw + (size_t)(bn * 128 + r) * K + kt * 32 + cb * 8,
                  Bs + (size_t)(i * 256 + w * 64) * 8);
    }
    __syncthreads();
    short8 af[4], bfr[4];
#pragma unroll
    for (int mf = 0; mf < 4; ++mf)
      af[mf] = *(const short8*)&As[(wr * 64 + mf * 16 + l15) * 32 + l4 * 8];
#pragma unroll
    for (int nf = 0; nf < 4; ++nf)
      bfr[nf] = *(const short8*)&Bs[(wc * 64 + nf * 16 + l15) * 32 + l4 * 8];
#pragma unroll
    for (int mf = 0; mf < 4; ++mf)
#pragma unroll
      for (int nf = 0; nf < 4; ++nf)
        acc[mf][nf] = MFMA16(af[mf], bfr[nf], acc[mf][nf]);
    __syncthreads();
  }

#pragma unroll
  for (int mf = 0; mf < 4; ++mf)
#pragma unroll
    for (int nf = 0; nf < 4; ++nf) {
      int col = bn * 128 + wc * 64 + nf * 16 + l15;
      float bv = bias[col];
#pragma unroll
      for (int j = 0; j < 4; ++j) {
        int row = bm * 128 + wr * 64 + mf * 16 + l4 * 4 + j;
        float val = (acc[mf][nf][j] + bv) * alpha;
        if (MODE == 1)      Cf[(size_t)row * N + col] = val;
        else if (MODE == 2) Cb[(size_t)col * S_LEN + row] = f2bf(val);  // transposed
        else                Cb[(size_t)row * N + col] = f2bf(val);
      }
    }
}

__global__ __launch_bounds__(256) void proj_qkv(
    const unsigned short* xq, const unsigned short* xk, const unsigned short* xv,
    const unsigned short* wq, const unsigned short* wk, const unsigned short* wv,
    unsigned short* Qp, unsigned short* Kp, unsigned short* Vt,
    const float* bq, const float* bk, const float* bv)
{
  __shared__ unsigned short As[128 * 32], Bs[128 * 32];
  switch (blockIdx.z) {
    case 0:  gemm128<0>(xq, wq, Qp, nullptr, bq, 0.125f, As, Bs); break; // 1/sqrt(64) folded
    case 1:  gemm128<0>(xk, wk, Kp, nullptr, bk, 1.0f,   As, Bs); break;
    default: gemm128<2>(xv, wv, Vt, nullptr, bv, 1.0f,   As, Bs); break; // V^T [1024][4096]
  }
}

__global__ __launch_bounds__(256) void proj_o(
    const unsigned short* ctx, const unsigned short* wo, float* out, const float* bo)
{
  __shared__ unsigned short As[128 * 32], Bs[128 * 32];
  gemm128<1>(ctx, wo, nullptr, out, bo, 1.0f, As, Bs);
}

// ---------------- fused flash attention ----------------
// 1024 blocks (XCD-swizzled), block = (head h, 64 q rows), 4 waves x 16 rows.
// SWAPPED QK^T: sc = mfma(K, Q) so lane owns row q=l15's 16 k-values in regs:
//   S[q=l15][k = nf*16 + l4*4 + reg] -> in-register softmax (2 shuffles/reduce).
// Defer-max (THR=8): skip O-rescale unless the tile max grows past m_run+8.
__global__ __launch_bounds__(256) void attn_fused(
    const unsigned short* __restrict__ Qp, const unsigned short* __restrict__ Kp,
    const unsigned short* __restrict__ Vt, unsigned short* __restrict__ ctx)
{
  __shared__ unsigned short Ks[2][64 * 64];
  __shared__ unsigned short Vts[2][64 * 64];
  __shared__ unsigned short Ps[4][16 * 72];  // per-wave P[q][k], stride 72 (16B-aligned, padded)

  // bijective XCD swizzle: 1024 blocks, 8 XCDs, 128 consecutive wg per XCD (= 2 heads)
  int bid = blockIdx.x;
  int wg = (bid & 7) * 128 + (bid >> 3);
  int h = wg >> 6, qt = wg & 63;

  int t = threadIdx.x, lane = t & 63, w = t >> 6;
  int l15 = lane & 15, l4 = lane >> 4;

  // Q fragments in registers (already scaled by 1/8 in projection)
  short8 qf[2];
  int qrow0 = qt * 64 + w * 16;
#pragma unroll
  for (int ks = 0; ks < 2; ++ks)
    qf[ks] = *(const short8*)&Qp[(size_t)(qrow0 + l15) * DM + h * 64 + ks * 32 + l4 * 8];

  float4v acc_o[4] = {};
  float m_run = -INFINITY, l_run = 0.f;

  unsigned short* Pw = Ps[w];

#define STAGE_KV(buf, kt) do {                                              \
    _Pragma("unroll")                                                       \
    for (int i = 0; i < 2; ++i) {                                           \
      int ci = i * 256 + t;                                                 \
      int r = ci >> 3, p = ci & 7;                                          \
      int lb = p ^ (r & 7);                                                 \
      GLOAD_LDS16(Kp + (size_t)((kt) * 64 + r) * DM + h * 64 + lb * 8,      \
                  &Ks[buf][(size_t)(i * 256 + w * 64) * 8]);                \
      GLOAD_LDS16(Vt + (size_t)(h * 64 + r) * S_LEN + (kt) * 64 + lb * 8,   \
                  &Vts[buf][(size_t)(i * 256 + w * 64) * 8]);               \
    }                                                                       \
  } while (0)

  STAGE_KV(0, 0);
  __syncthreads();
  int cur = 0;

  for (int kt = 0; kt < 64; ++kt) {
    if (kt + 1 < 64) STAGE_KV(cur ^ 1, kt + 1);   // prefetch next tile (in flight under compute)

    // ---- QK^T (swapped: A = K rows, B = Q rows) ----
    float4v sc[4] = {};
#pragma unroll
    for (int nf = 0; nf < 4; ++nf)
#pragma unroll
      for (int ks = 0; ks < 2; ++ks) {
        int row = nf * 16 + l15;
        int pb = (ks * 4 + l4) ^ (row & 7);
        short8 kf = *(const short8*)&Ks[cur][row * 64 + pb * 8];
        sc[nf] = MFMA16(kf, qf[ks], sc[nf]);
      }

    // ---- in-register online softmax for row q = l15 ----
    float mx = fmaxf(fmaxf(sc[0][0], sc[0][1]), fmaxf(sc[0][2], sc[0][3]));
#pragma unroll
    for (int nf = 1; nf < 4; ++nf)
      mx = fmaxf(mx, fmaxf(fmaxf(sc[nf][0], sc[nf][1]), fmaxf(sc[nf][2], sc[nf][3])));
    mx = fmaxf(mx, __shfl_xor(mx, 16));
    mx = fmaxf(mx, __shfl_xor(mx, 32));

    if (!__all(mx <= m_run + 8.f)) {     // defer-max: rescale rarely taken
      float mnew = fmaxf(m_run, mx);
      float corr = __expf(m_run - mnew);
      m_run = mnew;
      l_run *= corr;
#pragma unroll
      for (int j = 0; j < 4; ++j) {
        float cj = __shfl(corr, l4 * 4 + j);   // corr for PV row q = l4*4+j lives in lane q
#pragma unroll
        for (int nf2 = 0; nf2 < 4; ++nf2) acc_o[nf2][j] *= cj;
      }
    }

    float ps = 0.f;
#pragma unroll
    for (int nf = 0; nf < 4; ++nf) {
      ushort4v pk;
#pragma unroll
      for (int j = 0; j < 4; ++j) {
        float p = __expf(sc[nf][j] - m_run);
        ps += p;
        pk[j] = f2bf(p);
      }
      *(ushort4v*)&Pw[l15 * 72 + nf * 16 + l4 * 4] = pk;  // ds_write_b64
    }
    ps += __shfl_xor(ps, 16);
    ps += __shfl_xor(ps, 32);
    l_run += ps;

    // ---- P A-fragments from per-wave LDS (same-wave RAW, compiler waits lgkm) ----
    short8 pf[2];
#pragma unroll
    for (int kc = 0; kc < 2; ++kc)
      pf[kc] = *(const short8*)&Pw[l15 * 72 + kc * 32 + l4 * 8];

    // ---- PV: V^T B-fragments (swizzled read) ----
#pragma unroll
    for (int nfd = 0; nfd < 4; ++nfd)
#pragma unroll
      for (int kc = 0; kc < 2; ++kc) {
        int row = nfd * 16 + l15;
        int pb = (kc * 4 + l4) ^ (row & 7);
        short8 vf = *(const short8*)&Vts[cur][row * 64 + pb * 8];
        acc_o[nfd] = MFMA16(pf[kc], vf, acc_o[nfd]);
      }

    __syncthreads();   // drains prefetch (vmcnt auto) + all waves done with buf[cur]
    cur ^= 1;
  }
#undef STAGE_KV

  // ---- normalize + write ctx (bf16); l_run for row q lives in lane q ----
#pragma unroll
  for (int j = 0; j < 4; ++j) {
    float lj = __shfl(l_run, l4 * 4 + j);
    float inv = 1.0f / lj;
#pragma unroll
    for (int nfd = 0; nfd < 4; ++nfd) {
      int row = qt * 64 + w * 16 + l4 * 4 + j;
      int col = h * 64 + nfd * 16 + l15;
      ctx[(size_t)row * DM + col] = f2bf(acc_o[nfd][j] * inv);
    }
  }
}

// ---------------- launcher ----------------
extern "C" void kernel_launch(void* const* d_in, const int* in_sizes, int n_in,
                              void* d_out, int out_size, void* d_ws, size_t ws_size,
                              hipStream_t stream) {
  const float* q  = (const float*)d_in[0];
  const float* k  = (const float*)d_in[1];
  const float* v  = (const float*)d_in[2];
  const float* wq = (const float*)d_in[3];
  const float* bq = (const float*)d_in[4];
  const float* wk = (const float*)d_in[5];
  const float* bk = (const float*)d_in[6];
  const float* wv = (const float*)d_in[7];
  const float* bv = (const float*)d_in[8];
  const float* wo = (const float*)d_in[9];
  const float* bo = (const float*)d_in[10];

  unsigned short* ws  = (unsigned short*)d_ws;
  unsigned short* qb  = ws;                 // 4M elems (reused as ctx later)
  unsigned short* kb  = ws + 4194304u;
  unsigned short* vb  = ws + 8388608u;
  unsigned short* wqb = ws + 12582912u;
  unsigned short* wkb = ws + 13631488u;
  unsigned short* wvb = ws + 14680064u;
  unsigned short* wob = ws + 15728640u;
  unsigned short* Qp  = ws + 16777216u;
  unsigned short* Kp  = ws + 20971520u;
  unsigned short* Vt  = ws + 25165824u;     // V^T [1024][4096]
  unsigned short* ctx = qb;                 // safe reuse: qb consumed by proj_qkv before attn
  float* out = (float*)d_out;

  cast_all<<<dim3(1024, 7), 256, 0, stream>>>(q, k, v, wq, wk, wv, wo, ws);
  proj_qkv<<<dim3(32, 8, 3), 256, 0, stream>>>(qb, kb, vb, wqb, wkb, wvb, Qp, Kp, Vt, bq, bk, bv);
  attn_fused<<<dim3(1024), 256, 0, stream>>>(Qp, Kp, Vt, ctx);
  proj_o<<<dim3(32, 8), 256, 0, stream>>>(ctx, wob, out, bo);
}

// Round 6
// 191.142 us; speedup vs baseline: 1.8207x; 1.2703x over previous
//
#include <hip/hip_runtime.h>
#include <stdint.h>

#define S_LEN 4096
#define DM 1024
#define NH 16

typedef __attribute__((ext_vector_type(8))) short short8;
typedef __attribute__((ext_vector_type(4))) float float4v;
typedef __attribute__((ext_vector_type(4))) unsigned short ushort4v;

typedef __attribute__((address_space(1))) const void* as1cvp;
typedef __attribute__((address_space(3))) void* as3vp;

#define MFMA16(a, b, c) __builtin_amdgcn_mfma_f32_16x16x32_bf16((a), (b), (c), 0, 0, 0)
#define GLOAD_LDS16(g, l) \
  __builtin_amdgcn_global_load_lds((as1cvp)(g), (as3vp)(l), 16, 0, 0)

__device__ __forceinline__ unsigned short f2bf(float f) {
  unsigned u = __float_as_uint(f);
  u += 0x7fffu + ((u >> 16) & 1u);
  return (unsigned short)(u >> 16);
}

// ---------------- cast fp32 -> bf16 into workspace ----------------
__global__ __launch_bounds__(256) void cast_all(
    const float* __restrict__ q, const float* __restrict__ k, const float* __restrict__ v,
    const float* __restrict__ wq, const float* __restrict__ wk, const float* __restrict__ wv,
    const float* __restrict__ wo, unsigned short* __restrict__ dst)
{
  const float* src; size_t off; int n;
  switch (blockIdx.y) {
    case 0: src = q;  off = 0u;        n = 4194304; break;
    case 1: src = k;  off = 4194304u;  n = 4194304; break;
    case 2: src = v;  off = 8388608u;  n = 4194304; break;
    case 3: src = wq; off = 12582912u; n = 1048576; break;
    case 4: src = wk; off = 13631488u; n = 1048576; break;
    case 5: src = wv; off = 14680064u; n = 1048576; break;
    default: src = wo; off = 15728640u; n = 1048576; break;
  }
  int nv = n >> 2;
  for (int i = blockIdx.x * blockDim.x + threadIdx.x; i < nv; i += gridDim.x * blockDim.x) {
    float4v val = ((const float4v*)src)[i];
    ushort4v o;
    o.x = f2bf(val.x); o.y = f2bf(val.y); o.z = f2bf(val.z); o.w = f2bf(val.w);
    ((ushort4v*)(dst + off))[i] = o;
  }
}

// ---------------- 128x128 bt-GEMM tile (m97 structure) ----------------
// MODE 0: bf16 row-major out; MODE 1: f32 row-major out; MODE 2: bf16 TRANSPOSED out [N][4096]
template<int MODE>
__device__ __forceinline__ void gemm128(
    const unsigned short* __restrict__ A, const unsigned short* __restrict__ Bw,
    unsigned short* Cb, float* Cf, const float* __restrict__ bias, float alpha,
    unsigned short* As, unsigned short* Bs)
{
  const int K = 1024, N = 1024;
  int bm = blockIdx.x, bn = blockIdx.y;
  int t = threadIdx.x, lane = t & 63, w = t >> 6;
  int l15 = lane & 15, l4 = lane >> 4;
  int wr = w >> 1, wc = w & 1;

  float4v acc[4][4] = {};

  for (int kt = 0; kt < K / 32; ++kt) {
#pragma unroll
    for (int i = 0; i < 2; ++i) {
      int ci = i * 256 + t;
      int r = ci >> 2, cb = ci & 3;
      GLOAD_LDS16(A + (size_t)(bm * 128 + r) * K + kt * 32 + cb * 8,
                  As + (size_t)(i * 256 + w * 64) * 8);
      GLOAD_LDS16(Bw + (size_t)(bn * 128 + r) * K + kt * 32 + cb * 8,
                  Bs + (size_t)(i * 256 + w * 64) * 8);
    }
    __syncthreads();
    short8 af[4], bfr[4];
#pragma unroll
    for (int mf = 0; mf < 4; ++mf)
      af[mf] = *(const short8*)&As[(wr * 64 + mf * 16 + l15) * 32 + l4 * 8];
#pragma unroll
    for (int nf = 0; nf < 4; ++nf)
      bfr[nf] = *(const short8*)&Bs[(wc * 64 + nf * 16 + l15) * 32 + l4 * 8];
#pragma unroll
    for (int mf = 0; mf < 4; ++mf)
#pragma unroll
      for (int nf = 0; nf < 4; ++nf)
        acc[mf][nf] = MFMA16(af[mf], bfr[nf], acc[mf][nf]);
    __syncthreads();
  }

#pragma unroll
  for (int mf = 0; mf < 4; ++mf)
#pragma unroll
    for (int nf = 0; nf < 4; ++nf) {
      int col = bn * 128 + wc * 64 + nf * 16 + l15;
      float bv = bias[col];
#pragma unroll
      for (int j = 0; j < 4; ++j) {
        int row = bm * 128 + wr * 64 + mf * 16 + l4 * 4 + j;
        float val = (acc[mf][nf][j] + bv) * alpha;
        if (MODE == 1)      Cf[(size_t)row * N + col] = val;
        else if (MODE == 2) Cb[(size_t)col * S_LEN + row] = f2bf(val);  // transposed
        else                Cb[(size_t)row * N + col] = f2bf(val);
      }
    }
}

__global__ __launch_bounds__(256) void proj_qkv(
    const unsigned short* xq, const unsigned short* xk, const unsigned short* xv,
    const unsigned short* wq, const unsigned short* wk, const unsigned short* wv,
    unsigned short* Qp, unsigned short* Kp, unsigned short* Vt,
    const float* bq, const float* bk, const float* bv)
{
  __shared__ unsigned short As[128 * 32], Bs[128 * 32];
  switch (blockIdx.z) {
    case 0:  gemm128<0>(xq, wq, Qp, nullptr, bq, 0.125f, As, Bs); break; // 1/sqrt(64) folded
    case 1:  gemm128<0>(xk, wk, Kp, nullptr, bk, 1.0f,   As, Bs); break;
    default: gemm128<2>(xv, wv, Vt, nullptr, bv, 1.0f,   As, Bs); break; // V^T [1024][4096]
  }
}

__global__ __launch_bounds__(256) void proj_o(
    const unsigned short* ctx, const unsigned short* wo, float* out, const float* bo)
{
  __shared__ unsigned short As[128 * 32], Bs[128 * 32];
  gemm128<1>(ctx, wo, nullptr, out, bo, 1.0f, As, Bs);
}

// ---------------- fused flash attention ----------------
// 512 blocks (XCD-swizzled) x 512 threads (8 waves), block = (head, 128 q rows),
// wave = 16 q rows. KV tile 64, static unroll-2 double buffer, all DS addresses
// precomputed per-lane (immediate-offset reads). Swapped QK^T -> in-register
// softmax; P via cvt_pk_bf16 + per-wave LDS round-trip; defer-max THR=8.
template<int BUF>
__device__ __forceinline__ void attn_tile(
    int kt,
    const unsigned short* kb0, const unsigned short* kb1,
    const unsigned short* vb0, const unsigned short* vb1,
    unsigned short* pw, const unsigned short* pr,
    const unsigned short* kg, const unsigned short* vg,
    unsigned short* kls, unsigned short* vls,
    const short8 (&qf)[2], float4v (&acc_o)[4], float& m_run, float& l_run,
    int l4)
{
  if (kt + 1 < 64) {   // prefetch next tile into the other buffer
    GLOAD_LDS16(kg + (size_t)(kt + 1) * (64 * DM), kls + (1 - BUF) * 4096);
    GLOAD_LDS16(vg + (kt + 1) * 64, vls + (1 - BUF) * 4096);
  }

  // ---- QK^T (swapped: A = K rows, B = Q rows) ----
  float4v sc[4];
#pragma unroll
  for (int nf = 0; nf < 4; ++nf) {
    short8 kf0 = *(const short8*)(kb0 + BUF * 4096 + nf * 1024);
    short8 kf1 = *(const short8*)(kb1 + BUF * 4096 + nf * 1024);
    float4v z = {0.f, 0.f, 0.f, 0.f};
    z = MFMA16(kf0, qf[0], z);
    sc[nf] = MFMA16(kf1, qf[1], z);
  }

  // ---- row max (q = l15), max3-friendly nesting ----
  float mx = fmaxf(fmaxf(fmaxf(sc[0][0], sc[0][1]), sc[0][2]), sc[0][3]);
#pragma unroll
  for (int nf = 1; nf < 4; ++nf)
    mx = fmaxf(fmaxf(fmaxf(fmaxf(mx, sc[nf][0]), sc[nf][1]), sc[nf][2]), sc[nf][3]);
  mx = fmaxf(mx, __shfl_xor(mx, 16));
  mx = fmaxf(mx, __shfl_xor(mx, 32));

  if (!__all(mx <= m_run + 8.f)) {   // defer-max: rarely taken
    float mnew = fmaxf(m_run, mx);
    float corr = __expf(m_run - mnew);
    m_run = mnew;
    l_run *= corr;
#pragma unroll
    for (int j = 0; j < 4; ++j) {
      float cj = __shfl(corr, l4 * 4 + j);
#pragma unroll
      for (int nf2 = 0; nf2 < 4; ++nf2) acc_o[nf2][j] *= cj;
    }
  }

  // ---- exp + packed bf16 conversion + P write ----
  float ps = 0.f;
#pragma unroll
  for (int nf = 0; nf < 4; ++nf) {
    float p0 = __expf(sc[nf][0] - m_run);
    float p1 = __expf(sc[nf][1] - m_run);
    float p2 = __expf(sc[nf][2] - m_run);
    float p3 = __expf(sc[nf][3] - m_run);
    ps += (p0 + p1) + (p2 + p3);
    unsigned lo, hi;
    asm("v_cvt_pk_bf16_f32 %0, %1, %2" : "=v"(lo) : "v"(p0), "v"(p1));
    asm("v_cvt_pk_bf16_f32 %0, %1, %2" : "=v"(hi) : "v"(p2), "v"(p3));
    uint2 u; u.x = lo; u.y = hi;
    *(uint2*)(pw + nf * 16) = u;   // ds_write_b64
  }
  ps += __shfl_xor(ps, 16);
  ps += __shfl_xor(ps, 32);
  l_run += ps;

  // ---- P A-fragments (same-wave RAW through LDS) ----
  short8 pf[2];
#pragma unroll
  for (int kc = 0; kc < 2; ++kc)
    pf[kc] = *(const short8*)(pr + kc * 32);

  // ---- PV ----
#pragma unroll
  for (int nfd = 0; nfd < 4; ++nfd) {
    short8 vf0 = *(const short8*)(vb0 + BUF * 4096 + nfd * 1024);
    short8 vf1 = *(const short8*)(vb1 + BUF * 4096 + nfd * 1024);
    acc_o[nfd] = MFMA16(pf[0], vf0, acc_o[nfd]);
    acc_o[nfd] = MFMA16(pf[1], vf1, acc_o[nfd]);
  }
  __syncthreads();   // drains prefetch (vmcnt) + all waves done with buf[BUF]
}

__global__ __launch_bounds__(512) void attn_fused(
    const unsigned short* __restrict__ Qp, const unsigned short* __restrict__ Kp,
    const unsigned short* __restrict__ Vt, unsigned short* __restrict__ ctx)
{
  __shared__ unsigned short Ks[2][64 * 64];
  __shared__ unsigned short Vts[2][64 * 64];
  __shared__ unsigned short Ps[8][16 * 72];

  // bijective XCD swizzle: 512 blocks, 64 consecutive wg per XCD
  int bid = blockIdx.x;
  int wg = (bid & 7) * 64 + (bid >> 3);
  int h = wg >> 5, qt = wg & 31;

  int t = threadIdx.x, lane = t & 63, w = t >> 6;
  int l15 = lane & 15, l4 = lane >> 4;

  // Q fragments (already scaled by 1/8 in projection)
  short8 qf[2];
  int qrow0 = qt * 128 + w * 16;
#pragma unroll
  for (int ks = 0; ks < 2; ++ks)
    qf[ks] = *(const short8*)&Qp[(size_t)(qrow0 + l15) * DM + h * 64 + ks * 32 + l4 * 8];

  float4v acc_o[4] = {};
  float m_run = -INFINITY, l_run = 0.f;

  // ---- precomputed per-lane LDS addresses ----
  const int swz = l15 & 7;
  const unsigned short* kb0 = &Ks[0][l15 * 64 + ((l4) ^ swz) * 8];
  const unsigned short* kb1 = &Ks[0][l15 * 64 + ((4 + l4) ^ swz) * 8];
  const unsigned short* vb0 = &Vts[0][l15 * 64 + ((l4) ^ swz) * 8];
  const unsigned short* vb1 = &Vts[0][l15 * 64 + ((4 + l4) ^ swz) * 8];
  unsigned short* pw = &Ps[w][l15 * 72 + l4 * 4];
  const unsigned short* pr = &Ps[w][l15 * 72 + l4 * 8];

  // ---- staging addresses (512 threads: 1 K-load + 1 V-load each per tile) ----
  int sr = t >> 3, sp = t & 7;
  int slb = sp ^ (sr & 7);
  const unsigned short* kg = Kp + (size_t)sr * DM + h * 64 + slb * 8;
  const unsigned short* vg = Vt + (size_t)(h * 64 + sr) * S_LEN + slb * 8;
  unsigned short* kls = &Ks[0][t * 8];
  unsigned short* vls = &Vts[0][t * 8];

  GLOAD_LDS16(kg, kls);
  GLOAD_LDS16(vg, vls);
  __syncthreads();

  for (int kt = 0; kt < 64; kt += 2) {
    attn_tile<0>(kt,     kb0, kb1, vb0, vb1, pw, pr, kg, vg, kls, vls, qf, acc_o, m_run, l_run, l4);
    attn_tile<1>(kt + 1, kb0, kb1, vb0, vb1, pw, pr, kg, vg, kls, vls, qf, acc_o, m_run, l_run, l4);
  }

  // ---- normalize + write ctx (bf16); l_run for row q lives in lane q ----
#pragma unroll
  for (int j = 0; j < 4; ++j) {
    float lj = __shfl(l_run, l4 * 4 + j);
    float inv = 1.0f / lj;
#pragma unroll
    for (int nfd = 0; nfd < 4; ++nfd) {
      int row = qrow0 + l4 * 4 + j;
      int col = h * 64 + nfd * 16 + l15;
      ctx[(size_t)row * DM + col] = f2bf(acc_o[nfd][j] * inv);
    }
  }
}

// ---------------- launcher ----------------
extern "C" void kernel_launch(void* const* d_in, const int* in_sizes, int n_in,
                              void* d_out, int out_size, void* d_ws, size_t ws_size,
                              hipStream_t stream) {
  const float* q  = (const float*)d_in[0];
  const float* k  = (const float*)d_in[1];
  const float* v  = (const float*)d_in[2];
  const float* wq = (const float*)d_in[3];
  const float* bq = (const float*)d_in[4];
  const float* wk = (const float*)d_in[5];
  const float* bk = (const float*)d_in[6];
  const float* wv = (const float*)d_in[7];
  const float* bv = (const float*)d_in[8];
  const float* wo = (const float*)d_in[9];
  const float* bo = (const float*)d_in[10];

  unsigned short* ws  = (unsigned short*)d_ws;
  unsigned short* qb  = ws;                 // 4M elems (reused as ctx later)
  unsigned short* kb  = ws + 4194304u;
  unsigned short* vb  = ws + 8388608u;
  unsigned short* wqb = ws + 12582912u;
  unsigned short* wkb = ws + 13631488u;
  unsigned short* wvb = ws + 14680064u;
  unsigned short* wob = ws + 15728640u;
  unsigned short* Qp  = ws + 16777216u;
  unsigned short* Kp  = ws + 20971520u;
  unsigned short* Vt  = ws + 25165824u;     // V^T [1024][4096]
  unsigned short* ctx = qb;                 // safe reuse: qb consumed by proj_qkv before attn
  float* out = (float*)d_out;

  cast_all<<<dim3(1024, 7), 256, 0, stream>>>(q, k, v, wq, wk, wv, wo, ws);
  proj_qkv<<<dim3(32, 8, 3), 256, 0, stream>>>(qb, kb, vb, wqb, wkb, wvb, Qp, Kp, Vt, bq, bk, bv);
  attn_fused<<<dim3(512), 512, 0, stream>>>(Qp, Kp, Vt, ctx);
  proj_o<<<dim3(32, 8), 256, 0, stream>>>(ctx, wob, out, bo);
}